// Round 7
// baseline (5388.496 us; speedup 1.0000x reference)
//
#include <hip/hip_runtime.h>
#include <hip/hip_bf16.h>
#include <cmath>
#include <complex>
#include <algorithm>

#define N_NODES  32768
#define FEAT_DIM 480
#define TMUL     224

__device__ __forceinline__ float siluf(float x){ return x * (1.0f/(1.0f + __expf(-x))); }

struct W3Pack { float v[363]; };

// ------------------------- host: exact Wigner-3j (mirrors reference) -------------------------
static double factd(int n){ double f=1.0; for(int i=2;i<=n;++i) f*=(double)i; return f; }

static double su2_cg(int j1,int j2,int j3,int m1,int m2,int m3){
  if (m1+m2 != m3) return 0.0;
  double pref = std::sqrt((2.0*j3+1.0)*factd(j3+j1-j2)*factd(j3-j1+j2)*factd(j1+j2-j3)/factd(j1+j2+j3+1));
  pref *= std::sqrt(factd(j3+m3)*factd(j3-m3)*factd(j1-m1)*factd(j1+m1)*factd(j2-m2)*factd(j2+m2));
  double s=0.0;
  int vmin = std::max(0, std::max(j2-j3-m1, j1-j3+m2));
  int vmax = std::min(j2+m2, std::min(j1-m1, j1+j2-j3));
  for (int v=vmin; v<=vmax; ++v){
    double d = factd(v)*factd(j1+j2-j3-v)*factd(j1-m1-v)*factd(j2+m2-v)*factd(j3-j2+m1+v)*factd(j3-j1-m2+v);
    s += ((v&1)? -1.0 : 1.0)/d;
  }
  return pref*s;
}

typedef std::complex<double> cd;

static void qmat(int l, cd* q){                 // (2l+1)x(2l+1), row-major [row][col]
  int d=2*l+1;
  for (int a=0;a<d*d;++a) q[a]=cd(0,0);
  double is2 = 1.0/std::sqrt(2.0);
  for (int m=-l; m<0; ++m){
    int am=-m;
    q[(l+m)*d + (l+am)] = cd(is2,0);
    q[(l+m)*d + (l-am)] = cd(0,-is2);
  }
  q[l*d+l] = cd(1,0);
  for (int m=1;m<=l;++m){
    double sg = (m&1)? -1.0:1.0;
    q[(l+m)*d + (l+m)] = cd(sg*is2,0);
    q[(l+m)*d + (l-m)] = cd(0,sg*is2);
  }
  cd f = (l==0)? cd(1,0) : (l==1? cd(0,-1) : cd(-1,0)); // (-i)^l for l<=2
  for (int a=0;a<d*d;++a) q[a]*=f;
}

static void wigner3j(int l1,int l2,int l3, float* out){
  int d1=2*l1+1,d2=2*l2+1,d3=2*l3+1;
  double Cc[5][5][5] = {};
  for (int m1=-l1;m1<=l1;++m1) for (int m2=-l2;m2<=l2;++m2){
    int m3=m1+m2;
    if (m3>=-l3 && m3<=l3) Cc[l1+m1][l2+m2][l3+m3] = su2_cg(l1,l2,l3,m1,m2,m3);
  }
  cd q1[25],q2[25],q3[25];
  qmat(l1,q1); qmat(l2,q2); qmat(l3,q3);
  double re[125], im[125];
  double nr=0, ni=0;
  for (int i=0;i<d1;++i) for (int j=0;j<d2;++j) for (int k=0;k<d3;++k){
    cd s(0,0);
    for (int a=0;a<d1;++a) for (int b=0;b<d2;++b) for (int c=0;c<d3;++c){
      double cc = Cc[a][b][c];
      if (cc != 0.0) s += q1[a*d1+i]*q2[b*d2+j]*std::conj(q3[c*d3+k])*cc;
    }
    int o=(i*d2+j)*d3+k;
    re[o]=s.real(); im[o]=s.imag();
    nr += s.real()*s.real(); ni += s.imag()*s.imag();
  }
  bool useRe = std::sqrt(nr) >= std::sqrt(ni);
  double nrm = std::sqrt(useRe? nr : ni);
  for (int o=0;o<d1*d2*d3;++o) out[o] = (float)((useRe? re[o] : im[o]) / nrm);
}

static W3Pack build_w3(){
  W3Pack W;
  wigner3j(0,0,0, W.v+0);
  wigner3j(0,1,1, W.v+1);
  wigner3j(0,2,2, W.v+10);
  wigner3j(1,0,1, W.v+35);
  wigner3j(1,1,0, W.v+44);
  wigner3j(1,1,2, W.v+53);
  wigner3j(1,2,1, W.v+98);
  wigner3j(2,0,2, W.v+143);
  wigner3j(2,1,1, W.v+168);
  wigner3j(2,2,0, W.v+213);
  wigner3j(2,2,2, W.v+238);
  return W;
}

// ------------------------- naive CG path: thread u owns row u, computes its own t -------------------------
template<int M1,int M2,int NI,int NJ,int NK,int I1OFF,int I2OFF,int WOFF,int CGOFF,int COFF>
__device__ __forceinline__ void path_naive(
    const float* __restrict__ tpw, const W3Pack& W,
    const float* sF, const float* sP, float* sC, int tid)
{
  if (tid < M1){
    const float rs = (M2==128)? 0.08838834764831845f : (M2==64? 0.125f : 0.17677669529663687f);
    float t[NJ];
    #pragma unroll
    for (int j=0;j<NJ;++j){
      float a = 0.f;
      for (int v=0; v<M2; ++v) a += sP[I2OFF + v*NJ + j] * tpw[WOFF + tid*M2 + v];
      t[j] = a*rs;
    }
    float y[NK];
    #pragma unroll
    for (int k=0;k<NK;++k) y[k]=0.f;
    #pragma unroll
    for (int i=0;i<NI;++i){
      #pragma unroll
      for (int j=0;j<NJ;++j){
        const float p = sF[I1OFF + tid*NI + i] * t[j];
        #pragma unroll
        for (int k=0;k<NK;++k) y[k] += p * W.v[CGOFF + (i*NJ + j)*NK + k];
      }
    }
    #pragma unroll
    for (int k=0;k<NK;++k) sC[COFF + tid*NK + k] = y[k];
  }
}

// ------------------------- fused naive kernel: 1 node per block, f32 in / f32 out -------------------------
__global__ __launch_bounds__(256) void n_fused(
  const float* __restrict__ feat,
  const float* __restrict__ w0, const float* __restrict__ w1, const float* __restrict__ w2,
  const float* __restrict__ pgw1, const float* __restrict__ pgb1,
  const float* __restrict__ pgw2, const float* __restrict__ pgb2,
  const float* __restrict__ tpw,
  const float* __restrict__ pw0, const float* __restrict__ pw1, const float* __restrict__ pw2,
  const float* __restrict__ qgw1, const float* __restrict__ qgb1,
  const float* __restrict__ qgw2, const float* __restrict__ qgb2,
  float* __restrict__ outp, const W3Pack W)
{
  __shared__ float sF[FEAT_DIM], sP[FEAT_DIM], sLin[FEAT_DIM], sPost[FEAT_DIM];
  __shared__ float sC[2368];
  __shared__ float sInv[256], sVn[TMUL], sH[TMUL], sG[TMUL], sRed[2];

  const int c = threadIdx.x;
  const size_t n = blockIdx.x;

  for (int p=c; p<FEAT_DIM; p+=256) sF[p] = feat[n*FEAT_DIM + p];
  __syncthreads();

  // ======== pre linear (e3nn per-l channel mix) ========
  if (c < 128){
    float a=0.f;
    for (int u=0;u<128;++u) a += sF[u]*w0[u*128 + c];
    sLin[c] = a*0.08838834764831845f;                       // 1/sqrt(128)
  } else if (c < 192){
    const int v=c-128;
    float a0=0.f,a1=0.f,a2=0.f;
    for (int u=0;u<64;++u){
      const float wv = w1[u*64 + v];
      a0 += sF[128+u*3+0]*wv; a1 += sF[128+u*3+1]*wv; a2 += sF[128+u*3+2]*wv;
    }
    sLin[128+v*3+0]=a0*0.125f; sLin[128+v*3+1]=a1*0.125f; sLin[128+v*3+2]=a2*0.125f;
  } else if (c < 224){
    const int v=c-192;
    float a[5]={0.f,0.f,0.f,0.f,0.f};
    for (int u=0;u<32;++u){
      const float wv = w2[u*32 + v];
      #pragma unroll
      for (int i=0;i<5;++i) a[i] += sF[320+u*5+i]*wv;
    }
    #pragma unroll
    for (int i=0;i<5;++i) sLin[320+v*5+i]=a[i]*0.17677669529663687f; // 1/sqrt(32)
  }

  // ======== pre normgate ========
  {
    float inv = 0.f;   // thread's own sLin values — no sync needed yet
    if (c < 128) inv = sLin[c];
    else if (c < 192){ const int v=c-128; float s=0.f;
      for (int i=0;i<3;++i){ float x=sLin[128+v*3+i]; s+=x*x; } inv=sqrtf(s+1e-12f); }
    else if (c < 224){ const int v=c-192; float s=0.f;
      for (int i=0;i<5;++i){ float x=sLin[320+v*5+i]; s+=x*x; } inv=sqrtf(s+1e-12f); }
    sInv[c] = inv;
  }
  __syncthreads();
  if (c==0){
    float s=0.f, s2=0.f;
    for (int i=0;i<TMUL;++i){ s += sInv[i]; s2 += sInv[i]*sInv[i]; }
    const float m = s*(1.f/224.f);
    sRed[0]=m; sRed[1]=rsqrtf(s2*(1.f/224.f) - m*m + 1e-5f);
  }
  __syncthreads();
  if (c < TMUL) sVn[c] = (sInv[c]-sRed[0])*sRed[1];
  __syncthreads();
  if (c < TMUL){
    float a=0.f;
    for (int i=0;i<TMUL;++i) a += sVn[i]*pgw1[i*TMUL + c];
    sH[c] = siluf(a + pgb1[c]);
  }
  __syncthreads();
  if (c < TMUL){
    float a=0.f;
    for (int i=0;i<TMUL;++i) a += sH[i]*pgw2[i*TMUL + c];
    sG[c] = siluf(a + pgb2[c]);
  }
  __syncthreads();
  // gated pre -> sP
  if (c < 128) sP[c] = sLin[c]*sG[c];
  else if (c < 192){ const int b=128+(c-128)*3; for (int i=0;i<3;++i) sP[b+i]=sLin[b+i]*sG[c]; }
  else if (c < 224){ const int b=320+(c-192)*5; for (int i=0;i<5;++i) sP[b+i]=sLin[b+i]*sG[c]; }
  __syncthreads();

  // ======== CG coupling (disjoint sC writes; single sync after) ========
  //           M1   M2 NI NJ NK I1OFF I2OFF  WOFF CGOFF  COFF
  path_naive<128,128, 1, 1, 1,   0,    0,     0,    0,    0>(tpw,W,sF,sP,sC,c);
  path_naive<128, 64, 1, 3, 3,   0,  128, 16384,    1,  224>(tpw,W,sF,sP,sC,c);
  path_naive<128, 32, 1, 5, 5,   0,  320, 24576,   10, 1088>(tpw,W,sF,sP,sC,c);
  path_naive< 64,128, 3, 1, 3, 128,    0, 28672,   35,  608>(tpw,W,sF,sP,sC,c);
  path_naive< 64, 64, 3, 3, 1, 128,  128, 36864,   44,  128>(tpw,W,sF,sP,sC,c);
  path_naive< 64, 64, 3, 3, 5, 128,  128, 40960,   53, 1728>(tpw,W,sF,sP,sC,c);
  path_naive< 64, 32, 3, 5, 3, 128,  320, 45056,   98,  800>(tpw,W,sF,sP,sC,c);
  path_naive< 32,128, 5, 1, 5, 320,    0, 47104,  143, 2048>(tpw,W,sF,sP,sC,c);
  path_naive< 32, 64, 5, 3, 3, 320,  128, 51200,  168,  992>(tpw,W,sF,sP,sC,c);
  path_naive< 32, 32, 5, 5, 1, 320,  320, 53248,  213,  192>(tpw,W,sF,sP,sC,c);
  path_naive< 32, 32, 5, 5, 5, 320,  320, 54272,  238, 2208>(tpw,W,sF,sP,sC,c);
  __syncthreads();

  // ======== post linear ========
  if (c < 128){
    float a=0.f;
    for (int u=0;u<224;++u) a += sC[u]*pw0[u*128 + c];
    sPost[c] = a*0.06681531047810609f;                      // 1/sqrt(224)
  } else if (c < 192){
    const int v=c-128;
    float a0=0.f,a1=0.f,a2=0.f;
    for (int u=0;u<288;++u){
      const float wv = pw1[u*64 + v];
      a0 += sC[224+u*3+0]*wv; a1 += sC[224+u*3+1]*wv; a2 += sC[224+u*3+2]*wv;
    }
    sPost[128+v*3+0]=a0*0.05892556509887896f;               // 1/sqrt(288)
    sPost[128+v*3+1]=a1*0.05892556509887896f;
    sPost[128+v*3+2]=a2*0.05892556509887896f;
  } else if (c < 224){
    const int v=c-192;
    float a[5]={0.f,0.f,0.f,0.f,0.f};
    for (int u=0;u<256;++u){
      const float wv = pw2[u*32 + v];
      #pragma unroll
      for (int i=0;i<5;++i) a[i] += sC[1088+u*5+i]*wv;
    }
    #pragma unroll
    for (int i=0;i<5;++i) sPost[320+v*5+i]=a[i]*0.0625f;    // 1/sqrt(256)
  }

  // ======== post normgate ========
  {
    float inv = 0.f;
    if (c < 128) inv = sPost[c];
    else if (c < 192){ const int v=c-128; float s=0.f;
      for (int i=0;i<3;++i){ float x=sPost[128+v*3+i]; s+=x*x; } inv=sqrtf(s+1e-12f); }
    else if (c < 224){ const int v=c-192; float s=0.f;
      for (int i=0;i<5;++i){ float x=sPost[320+v*5+i]; s+=x*x; } inv=sqrtf(s+1e-12f); }
    sInv[c] = inv;
  }
  __syncthreads();
  if (c==0){
    float s=0.f, s2=0.f;
    for (int i=0;i<TMUL;++i){ s += sInv[i]; s2 += sInv[i]*sInv[i]; }
    const float m = s*(1.f/224.f);
    sRed[0]=m; sRed[1]=rsqrtf(s2*(1.f/224.f) - m*m + 1e-5f);
  }
  __syncthreads();
  if (c < TMUL) sVn[c] = (sInv[c]-sRed[0])*sRed[1];
  __syncthreads();
  if (c < TMUL){
    float a=0.f;
    for (int i=0;i<TMUL;++i) a += sVn[i]*qgw1[i*TMUL + c];
    sH[c] = siluf(a + qgb1[c]);
  }
  __syncthreads();
  if (c < TMUL){
    float a=0.f;
    for (int i=0;i<TMUL;++i) a += sH[i]*qgw2[i*TMUL + c];
    sG[c] = siluf(a + qgb2[c]);
  }
  __syncthreads();

  // ======== final: out = feat + pre + gated post (f32 out) ========
  if (c < 128){
    outp[n*FEAT_DIM + c] = sF[c] + sP[c] + sPost[c]*sG[c];
  } else if (c < 192){
    const int b=128+(c-128)*3;
    for (int i=0;i<3;++i)
      outp[n*FEAT_DIM + b+i] = sF[b+i] + sP[b+i] + sPost[b+i]*sG[c];
  } else if (c < 224){
    const int b=320+(c-192)*5;
    for (int i=0;i<5;++i)
      outp[n*FEAT_DIM + b+i] = sF[b+i] + sP[b+i] + sPost[b+i]*sG[c];
  }
}

// ------------------------- launch -------------------------
extern "C" void kernel_launch(void* const* d_in, const int* in_sizes, int n_in,
                              void* d_out, int out_size, void* d_ws, size_t ws_size,
                              hipStream_t stream)
{
  (void)in_sizes; (void)n_in; (void)out_size; (void)d_ws; (void)ws_size;
  const float* feat  = (const float*)d_in[0];
  const float* prw0  = (const float*)d_in[1];
  const float* prw1  = (const float*)d_in[2];
  const float* prw2  = (const float*)d_in[3];
  const float* pngw1 = (const float*)d_in[4];
  const float* pngb1 = (const float*)d_in[5];
  const float* pngw2 = (const float*)d_in[6];
  const float* pngb2 = (const float*)d_in[7];
  const float* tpw   = (const float*)d_in[8];
  const float* pow0  = (const float*)d_in[9];
  const float* pow1  = (const float*)d_in[10];
  const float* pow2  = (const float*)d_in[11];
  const float* qngw1 = (const float*)d_in[12];
  const float* qngb1 = (const float*)d_in[13];
  const float* qngw2 = (const float*)d_in[14];
  const float* qngb2 = (const float*)d_in[15];

  W3Pack W = build_w3();              // host-only, identical every call

  n_fused<<<dim3(N_NODES), dim3(256), 0, stream>>>(
      feat, prw0, prw1, prw2, pngw1, pngb1, pngw2, pngb2,
      tpw, pow0, pow1, pow2, qngw1, qngb1, qngw2, qngb2,
      (float*)d_out, W);
}